// Round 4
// baseline (3916.357 us; speedup 1.0000x reference)
//
#include <hip/hip_runtime.h>
#include <math.h>

// HGSA: 3x (mask-guided channel-attention MSA + LN + convFFN) on [2,64,256,256].
// External I/O fp32. Internal activations bf16, residual stream X fp32 (+bf16
// mirror Xb for GEMM inputs), weights staged to LDS as fp32.
// R2: dwconv vectorized 8ch/thread. R3: gemm64 had acc[64] SPILLED (VGPR=52,
// 180MB traffic/dispatch) -> __launch_bounds__(256,4) for 128-VGPR budget;
// QKV gemms read bf16 Xb (half the read traffic).

typedef unsigned short bhalf;
typedef unsigned int u32;

#define GEMM_GRID 512       // (B*N)/256
#define DW_GRID 4096        // (B*N*64/8)/256

__device__ __forceinline__ float bf2f(bhalf b) {
  union { u32 u; float f; } c; c.u = ((u32)b) << 16; return c.f;
}
__device__ __forceinline__ bhalf f2bf(float f) {
  union { float f; u32 u; } c; c.f = f;
  u32 lsb = (c.u >> 16) & 1u;
  c.u += 0x7fffu + lsb;           // round-to-nearest-even
  return (bhalf)(c.u >> 16);
}
__device__ __forceinline__ u32 pack2bf(float a, float b) {
  return (u32)f2bf(a) | ((u32)f2bf(b) << 16);
}
__device__ __forceinline__ void unpack2(u32 p, float& a, float& b) {
  union { u32 u; float f; } c0, c1;
  c0.u = p << 16; c1.u = p & 0xffff0000u;
  a = c0.f; b = c1.f;
}
__device__ __forceinline__ void unpack8(uint4 u, float* f) {
  unpack2(u.x, f[0], f[1]); unpack2(u.y, f[2], f[3]);
  unpack2(u.z, f[4], f[5]); unpack2(u.w, f[6], f[7]);
}
__device__ __forceinline__ float gelu_f(float v) {   // exact gelu
  return 0.5f * v * (1.0f + erff(v * 0.70710678118654752440f));
}

// ---------------- transposes ----------------
// MODE 0: x -> fp32 X AND bf16 Xb.  MODE 1: mask -> bf16 only.
template<int MODE>
__global__ __launch_bounds__(256) void nchw2nhwc(const float* __restrict__ in,
                                                 void* __restrict__ out,
                                                 bhalf* __restrict__ out2) {
  __shared__ float tile[64][65];
  int t = threadIdx.x;
  int b = blockIdx.x >> 10;
  int n0 = (blockIdx.x & 1023) << 6;
  #pragma unroll
  for (int j = 0; j < 16; ++j) {
    int idx = j * 256 + t;
    int c = idx >> 6, nn = idx & 63;
    tile[c][nn] = in[(((size_t)(b * 64 + c)) << 16) + n0 + nn];
  }
  __syncthreads();
  #pragma unroll
  for (int j = 0; j < 16; ++j) {
    int idx = j * 256 + t;
    int nn = idx >> 6, c = idx & 63;
    size_t o = ((((size_t)b << 16) + n0 + nn) << 6) + c;
    float v = tile[c][nn];
    if (MODE == 0) { ((float*)out)[o] = v; out2[o] = f2bf(v); }
    else           { ((bhalf*)out)[o] = f2bf(v); }
  }
}

__global__ __launch_bounds__(256) void nhwc2nchw(const float* __restrict__ in,
                                                 float* __restrict__ out) {
  __shared__ float tile[64][65];
  int t = threadIdx.x;
  int b = blockIdx.x >> 10;
  int n0 = (blockIdx.x & 1023) << 6;
  #pragma unroll
  for (int j = 0; j < 16; ++j) {
    int idx = j * 256 + t;
    int nn = idx >> 6, c = idx & 63;
    tile[c][nn] = in[((((size_t)b << 16) + n0 + nn) << 6) + c];
  }
  __syncthreads();
  #pragma unroll
  for (int j = 0; j < 16; ++j) {
    int idx = j * 256 + t;
    int c = idx >> 6, nn = idx & 63;
    out[(((size_t)(b * 64 + c)) << 16) + n0 + nn] = tile[c][nn];
  }
}

// ---------------- 64x64 GEMM (row-per-thread, fp32 weights in LDS) ----------------
#define EP_NONE 0
#define EP_BIAS 1
#define EP_GELU 2
#define EP_ACC  3   // fp32 out_ += result; optional bf16 mirror write (xbout)
#define EP_GATE 4   // store V (bf16); also store VG = V * aux
#define EP_RESID 5  // fp32 out_(X) += result + bias + aux(P bf16); writes xbout

// __launch_bounds__(256,4): 4 waves/EU min -> 128-VGPR cap; acc[64] stays in
// registers (R3 default alloc was 52 VGPR -> scratch spill, 69us/dispatch).
template<int EP, int INF32>
__global__ __launch_bounds__(256, 4) void gemm64(
    const void* __restrict__ in_, const float* __restrict__ w,
    const float* __restrict__ bias, void* __restrict__ out_,
    const bhalf* __restrict__ aux, bhalf* __restrict__ outg,
    bhalf* __restrict__ xbout, int wstride, int coloff)
{
  __shared__ float Ws[4096];
  __shared__ float bias_s[64];
  int t = threadIdx.x;
  {
    int k = t >> 2, c0 = (t & 3) << 4;
    const float4* wv = (const float4*)(w + (size_t)k * wstride + coloff + c0);
    float4* d = (float4*)&Ws[k * 64 + c0];
    d[0] = wv[0]; d[1] = wv[1]; d[2] = wv[2]; d[3] = wv[3];
    if ((EP == EP_BIAS || EP == EP_RESID) && t < 64) bias_s[t] = bias[t];
  }
  __syncthreads();
  size_t row = (size_t)blockIdx.x * 256 + t;
  float acc[64];
  #pragma unroll
  for (int i = 0; i < 64; ++i) acc[i] = 0.0f;

  if (INF32) {
    const float4* xv = (const float4*)((const float*)in_ + (row << 6));
    for (int kk = 0; kk < 16; ++kk) {
      float4 u = xv[kk];
      float xk[4] = {u.x, u.y, u.z, u.w};
      const float* wb = &Ws[(kk << 2) * 64];
      #pragma unroll
      for (int j = 0; j < 4; ++j) {
        float xj = xk[j];
        const float4* wr = (const float4*)(wb + j * 64);
        #pragma unroll
        for (int q = 0; q < 16; ++q) {
          float4 wvv = wr[q];
          acc[4*q+0] += xj * wvv.x; acc[4*q+1] += xj * wvv.y;
          acc[4*q+2] += xj * wvv.z; acc[4*q+3] += xj * wvv.w;
        }
      }
    }
  } else {
    const uint4* xv = (const uint4*)((const bhalf*)in_ + (row << 6));
    for (int kk = 0; kk < 8; ++kk) {
      uint4 u = xv[kk];
      float xk[8];
      unpack8(u, xk);
      const float* wb = &Ws[(kk << 3) * 64];
      #pragma unroll
      for (int j = 0; j < 8; ++j) {
        float xj = xk[j];
        const float4* wr = (const float4*)(wb + j * 64);
        #pragma unroll
        for (int q = 0; q < 16; ++q) {
          float4 wvv = wr[q];
          acc[4*q+0] += xj * wvv.x; acc[4*q+1] += xj * wvv.y;
          acc[4*q+2] += xj * wvv.z; acc[4*q+3] += xj * wvv.w;
        }
      }
    }
  }

  if (EP == EP_ACC) {
    float* xr = (float*)out_ + (row << 6);
    bhalf* xb = xbout ? (xbout + (row << 6)) : nullptr;
    #pragma unroll
    for (int q = 0; q < 16; ++q) {
      float4* x4 = (float4*)(xr + 4 * q);
      float4 v = *x4;
      v.x += acc[4*q+0]; v.y += acc[4*q+1]; v.z += acc[4*q+2]; v.w += acc[4*q+3];
      *x4 = v;
      if (xb) {
        uint2 s; s.x = pack2bf(v.x, v.y); s.y = pack2bf(v.z, v.w);
        *(uint2*)(xb + 4 * q) = s;
      }
    }
  } else if (EP == EP_RESID) {
    float* xr = (float*)out_ + (row << 6);
    bhalf* xb = xbout + (row << 6);
    const bhalf* pr = aux + (row << 6);
    #pragma unroll
    for (int cc = 0; cc < 4; ++cc) {
      const uint4* pv = (const uint4*)(pr + cc * 16);
      uint4 p0 = pv[0], p1 = pv[1];
      float pf[16];
      unpack8(p0, pf); unpack8(p1, pf + 8);
      #pragma unroll
      for (int q = 0; q < 4; ++q) {
        float4* x4 = (float4*)(xr + cc * 16 + 4 * q);
        float4 v = *x4;
        v.x += acc[cc*16+4*q+0] + bias_s[cc*16+4*q+0] + pf[4*q+0];
        v.y += acc[cc*16+4*q+1] + bias_s[cc*16+4*q+1] + pf[4*q+1];
        v.z += acc[cc*16+4*q+2] + bias_s[cc*16+4*q+2] + pf[4*q+2];
        v.w += acc[cc*16+4*q+3] + bias_s[cc*16+4*q+3] + pf[4*q+3];
        *x4 = v;
        uint2 s; s.x = pack2bf(v.x, v.y); s.y = pack2bf(v.z, v.w);
        *(uint2*)(xb + cc * 16 + 4 * q) = s;
      }
    }
  } else {
    bhalf* ob = (bhalf*)out_ + (row << 6);
    #pragma unroll
    for (int cc = 0; cc < 4; ++cc) {
      float vres[16];
      #pragma unroll
      for (int j = 0; j < 16; ++j) {
        float v = acc[cc * 16 + j];
        if (EP == EP_BIAS) v += bias_s[cc * 16 + j];
        if (EP == EP_GELU) v = gelu_f(v);
        vres[j] = v;
      }
      uint4 s0, s1;
      s0.x = pack2bf(vres[0],  vres[1]);  s0.y = pack2bf(vres[2],  vres[3]);
      s0.z = pack2bf(vres[4],  vres[5]);  s0.w = pack2bf(vres[6],  vres[7]);
      s1.x = pack2bf(vres[8],  vres[9]);  s1.y = pack2bf(vres[10], vres[11]);
      s1.z = pack2bf(vres[12], vres[13]); s1.w = pack2bf(vres[14], vres[15]);
      ((uint4*)(ob + cc * 16))[0] = s0;
      ((uint4*)(ob + cc * 16))[1] = s1;
      if (EP == EP_GATE) {
        const uint4* mv = (const uint4*)(aux + (row << 6) + cc * 16);
        uint4 m0 = mv[0], m1q = mv[1];
        float mf[16];
        unpack8(m0, mf); unpack8(m1q, mf + 8);
        uint4 g0, g1;
        g0.x = pack2bf(vres[0]*mf[0],   vres[1]*mf[1]);
        g0.y = pack2bf(vres[2]*mf[2],   vres[3]*mf[3]);
        g0.z = pack2bf(vres[4]*mf[4],   vres[5]*mf[5]);
        g0.w = pack2bf(vres[6]*mf[6],   vres[7]*mf[7]);
        g1.x = pack2bf(vres[8]*mf[8],   vres[9]*mf[9]);
        g1.y = pack2bf(vres[10]*mf[10], vres[11]*mf[11]);
        g1.z = pack2bf(vres[12]*mf[12], vres[13]*mf[13]);
        g1.w = pack2bf(vres[14]*mf[14], vres[15]*mf[15]);
        ((uint4*)(outg + (row << 6) + cc * 16))[0] = g0;
        ((uint4*)(outg + (row << 6) + cc * 16))[1] = g1;
      }
    }
  }
}

// ---------------- depthwise conv KxK SAME, NHWC, 64-channel slab ----------------
// 8 channels per thread via uint4 bf16 loads (16 B/lane).
// EPI: 0 = plain, 1 = gelu, 2 = mask gate: out = m1 * (sigmoid(acc + db) + 1)
template<int KS, int EPI>
__global__ __launch_bounds__(256) void dwconv(
    const bhalf* __restrict__ in, const float* __restrict__ wt,
    const float* __restrict__ db, const bhalf* __restrict__ m1,
    bhalf* __restrict__ out, int wstride, int woff)
{
  __shared__ float Ws[KS * KS * 64];
  __shared__ float db_s[64];
  int t = threadIdx.x;
  for (int idx = t; idx < KS * KS * 64; idx += 256) {
    int tap = idx >> 6, c = idx & 63;
    Ws[idx] = wt[tap * wstride + woff + c];
  }
  if (EPI == 2 && t < 64) db_s[t] = db[t];
  __syncthreads();
  size_t gid8 = (size_t)blockIdx.x * 256 + t;   // unit = 8 channels
  int c0 = (int)(gid8 & 7) << 3;
  size_t p = gid8 >> 3;
  int wx = (int)(p & 255), hy = (int)((p >> 8) & 255);
  size_t bb = p >> 16;
  const int R = KS >> 1;
  float acc[8];
  #pragma unroll
  for (int j = 0; j < 8; ++j) acc[j] = 0.0f;
  #pragma unroll
  for (int kh = 0; kh < KS; ++kh) {
    int y = hy + kh - R;
    if ((unsigned)y >= 256u) continue;
    #pragma unroll
    for (int kw = 0; kw < KS; ++kw) {
      int xw = wx + kw - R;
      if ((unsigned)xw >= 256u) continue;
      size_t off = (((bb << 8) + (size_t)y) << 8) + (size_t)xw;
      uint4 u = *(const uint4*)(in + (off << 6) + c0);
      float f[8];
      unpack8(u, f);
      const float* wr = &Ws[(kh * KS + kw) * 64 + c0];
      #pragma unroll
      for (int j = 0; j < 8; ++j) acc[j] += f[j] * wr[j];
    }
  }
  float r[8];
  if (EPI == 0) {
    #pragma unroll
    for (int j = 0; j < 8; ++j) r[j] = acc[j];
  } else if (EPI == 1) {
    #pragma unroll
    for (int j = 0; j < 8; ++j) r[j] = gelu_f(acc[j]);
  } else {
    uint4 mu = *(const uint4*)(m1 + (p << 6) + c0);
    float mf[8];
    unpack8(mu, mf);
    #pragma unroll
    for (int j = 0; j < 8; ++j) {
      float am = 1.0f / (1.0f + expf(-(acc[j] + db_s[c0 + j])));
      r[j] = mf[j] * (am + 1.0f);
    }
  }
  uint4 s;
  s.x = pack2bf(r[0], r[1]); s.y = pack2bf(r[2], r[3]);
  s.z = pack2bf(r[4], r[5]); s.w = pack2bf(r[6], r[7]);
  *(uint4*)(out + (p << 6) + c0) = s;
}

// ---------------- channel attention: S = K^T Q (per head) + channel norms ----------------
// grid: (chunk=32, h=4, b=2); 256 thr = (d 0..15, e4 0..3, row-quarter 0..3)
__global__ __launch_bounds__(256) void attn_partial(
    const bhalf* __restrict__ Q, const bhalf* __restrict__ K,
    float* __restrict__ S, float* __restrict__ nq, float* __restrict__ nk)
{
  __shared__ float Qs[1024], Ks[1024];
  int t = threadIdx.x;
  int d = t & 15, e4 = (t >> 4) & 3;
  int r0 = (t >> 6) << 4;
  int h = blockIdx.y, b = blockIdx.z;
  size_t base = ((((size_t)b << 16) + ((size_t)blockIdx.x << 11)) << 6) + (h << 4);
  int lr = t >> 2, lc = (t & 3) << 2;
  float4 acc = {0,0,0,0};
  float4 qss = {0,0,0,0};
  float kss = 0.0f;
  for (int s = 0; s < 32; ++s) {
    size_t g = base + ((size_t)(s * 64 + lr) << 6) + lc;
    uint2 qu = *(const uint2*)(Q + g);
    uint2 ku = *(const uint2*)(K + g);
    __syncthreads();
    float4 qf, kf;
    unpack2(qu.x, qf.x, qf.y); unpack2(qu.y, qf.z, qf.w);
    unpack2(ku.x, kf.x, kf.y); unpack2(ku.y, kf.z, kf.w);
    *(float4*)&Qs[t << 2] = qf;
    *(float4*)&Ks[t << 2] = kf;
    __syncthreads();
    #pragma unroll
    for (int rr = 0; rr < 16; ++rr) {
      int r = r0 + rr;
      float kv = Ks[(r << 4) + d];
      float4 qv = *(const float4*)&Qs[(r << 4) + (e4 << 2)];
      acc.x += kv * qv.x; acc.y += kv * qv.y; acc.z += kv * qv.z; acc.w += kv * qv.w;
      qss.x += qv.x * qv.x; qss.y += qv.y * qv.y; qss.z += qv.z * qv.z; qss.w += qv.w * qv.w;
      kss += kv * kv;
    }
  }
  float* Sp = S + ((((size_t)b * 4 + h) * 16 + d) << 4) + (e4 << 2);
  atomicAdd(Sp + 0, acc.x); atomicAdd(Sp + 1, acc.y);
  atomicAdd(Sp + 2, acc.z); atomicAdd(Sp + 3, acc.w);
  if (d == 0) {
    float* qp = nq + b * 64 + (h << 4) + (e4 << 2);
    atomicAdd(qp + 0, qss.x); atomicAdd(qp + 1, qss.y);
    atomicAdd(qp + 2, qss.z); atomicAdd(qp + 3, qss.w);
  }
  if (e4 == 0) atomicAdd(nk + b * 64 + (h << 4) + d, kss);
}

// softmax over e of S[d,e]*rescale/(max(||k_d||,eps)*max(||q_e||,eps)); writes TRANSPOSED [b][h][e][d]
__global__ void attn_softmax(const float* __restrict__ S, const float* __restrict__ nq,
                             const float* __restrict__ nk, const float* __restrict__ resc,
                             float* __restrict__ attnT)
{
  int b = blockIdx.x >> 2, h = blockIdx.x & 3;
  int d = threadIdx.x;
  if (d >= 16) return;
  float r = resc[h];
  float nkd = fmaxf(sqrtf(nk[b * 64 + h * 16 + d]), 1e-6f);
  float a[16];
  float m = -1e30f;
  #pragma unroll
  for (int e = 0; e < 16; ++e) {
    float nqe = fmaxf(sqrtf(nq[b * 64 + h * 16 + e]), 1e-6f);
    float v = S[(((b * 4 + h) * 16 + d) << 4) + e] * r / (nkd * nqe);
    a[e] = v;
    m = fmaxf(m, v);
  }
  float sum = 0.f;
  #pragma unroll
  for (int e = 0; e < 16; ++e) { a[e] = expf(a[e] - m); sum += a[e]; }
  float inv = 1.0f / sum;
  #pragma unroll
  for (int e = 0; e < 16; ++e)
    attnT[(((b * 4 + h) * 16 + e) << 4) + d] = a[e] * inv;
}

// o[n, h*16+d] = sum_e attnT[h][e][d] * VG[n, h*16+e]  (block-diagonal per-head 16x16)
__global__ __launch_bounds__(256, 4) void attnapply_kernel(
    const bhalf* __restrict__ vg, const float* __restrict__ attnT, bhalf* __restrict__ outO)
{
  __shared__ float As[1024];
  int t = threadIdx.x;
  int b = blockIdx.x >> 8;
  #pragma unroll
  for (int j = 0; j < 4; ++j) As[j * 256 + t] = attnT[b * 1024 + j * 256 + t];
  __syncthreads();
  size_t row = (size_t)blockIdx.x * 256 + t;
  const uint4* gv = (const uint4*)(vg + (row << 6));
  bhalf* orow = outO + (row << 6);
  #pragma unroll
  for (int h = 0; h < 4; ++h) {
    uint4 u0 = gv[2 * h], u1 = gv[2 * h + 1];
    float ve[16];
    unpack8(u0, ve); unpack8(u1, ve + 8);
    float4 oh0 = {0,0,0,0}, oh1 = {0,0,0,0}, oh2 = {0,0,0,0}, oh3 = {0,0,0,0};
    #pragma unroll
    for (int e = 0; e < 16; ++e) {
      const float4* ar = (const float4*)&As[(h * 16 + e) << 4];
      float vv = ve[e];
      float4 a0 = ar[0], a1 = ar[1], a2 = ar[2], a3 = ar[3];
      oh0.x += vv*a0.x; oh0.y += vv*a0.y; oh0.z += vv*a0.z; oh0.w += vv*a0.w;
      oh1.x += vv*a1.x; oh1.y += vv*a1.y; oh1.z += vv*a1.z; oh1.w += vv*a1.w;
      oh2.x += vv*a2.x; oh2.y += vv*a2.y; oh2.z += vv*a2.z; oh2.w += vv*a2.w;
      oh3.x += vv*a3.x; oh3.y += vv*a3.y; oh3.z += vv*a3.z; oh3.w += vv*a3.w;
    }
    uint4 s0, s1;
    s0.x = pack2bf(oh0.x, oh0.y); s0.y = pack2bf(oh0.z, oh0.w);
    s0.z = pack2bf(oh1.x, oh1.y); s0.w = pack2bf(oh1.z, oh1.w);
    s1.x = pack2bf(oh2.x, oh2.y); s1.y = pack2bf(oh2.z, oh2.w);
    s1.z = pack2bf(oh3.x, oh3.y); s1.w = pack2bf(oh3.z, oh3.w);
    ((uint4*)(orow + h * 16))[0] = s0;
    ((uint4*)(orow + h * 16))[1] = s1;
  }
}

// ---------------- LayerNorm over C=64 (reads fp32 X, writes bf16) ----------------
__global__ __launch_bounds__(256, 4) void ln_kernel(
    const float* __restrict__ x, const float* __restrict__ g,
    const float* __restrict__ bb, bhalf* __restrict__ out)
{
  __shared__ float gs[64], bs[64];
  int t = threadIdx.x;
  if (t < 64) { gs[t] = g[t]; bs[t] = bb[t]; }
  __syncthreads();
  size_t row = (size_t)blockIdx.x * 256 + t;
  const float4* xv = (const float4*)(x + (row << 6));
  float v[64];
  #pragma unroll
  for (int i = 0; i < 16; ++i) {
    float4 u = xv[i];
    v[4*i] = u.x; v[4*i+1] = u.y; v[4*i+2] = u.z; v[4*i+3] = u.w;
  }
  float s = 0.f;
  #pragma unroll
  for (int i = 0; i < 64; ++i) s += v[i];
  float mu = s * 0.015625f;
  float s2 = 0.f;
  #pragma unroll
  for (int i = 0; i < 64; ++i) { float dd = v[i] - mu; s2 += dd * dd; }
  float rstd = rsqrtf(s2 * 0.015625f + 1e-5f);
  bhalf* ob = out + (row << 6);
  #pragma unroll
  for (int cc = 0; cc < 4; ++cc) {
    float vr[16];
    #pragma unroll
    for (int j = 0; j < 16; ++j) {
      int c = cc * 16 + j;
      vr[j] = (v[c] - mu) * rstd * gs[c] + bs[c];
    }
    uint4 s0, s1;
    s0.x = pack2bf(vr[0],  vr[1]);  s0.y = pack2bf(vr[2],  vr[3]);
    s0.z = pack2bf(vr[4],  vr[5]);  s0.w = pack2bf(vr[6],  vr[7]);
    s1.x = pack2bf(vr[8],  vr[9]);  s1.y = pack2bf(vr[10], vr[11]);
    s1.z = pack2bf(vr[12], vr[13]); s1.w = pack2bf(vr[14], vr[15]);
    ((uint4*)(ob + cc * 16))[0] = s0;
    ((uint4*)(ob + cc * 16))[1] = s1;
  }
}

// ---------------- host orchestration ----------------
extern "C" void kernel_launch(void* const* d_in, const int* in_sizes, int n_in,
                              void* d_out, int out_size, void* d_ws, size_t ws_size,
                              hipStream_t stream)
{
  (void)in_sizes; (void)n_in; (void)out_size; (void)ws_size;
  const float* x_in    = (const float*)d_in[0];
  const float* mask_in = (const float*)d_in[1];
  const float* Wq    = (const float*)d_in[2];
  const float* Wk    = (const float*)d_in[3];
  const float* Wv    = (const float*)d_in[4];
  const float* resc  = (const float*)d_in[5];
  const float* Wp    = (const float*)d_in[6];
  const float* bp    = (const float*)d_in[7];
  const float* pe1   = (const float*)d_in[8];
  const float* pe2   = (const float*)d_in[9];
  const float* mm_w1 = (const float*)d_in[10];
  const float* mm_b1 = (const float*)d_in[11];
  const float* mm_w2 = (const float*)d_in[12];
  const float* mm_b2 = (const float*)d_in[13];
  const float* mm_dw = (const float*)d_in[14];
  const float* mm_db = (const float*)d_in[15];
  const float* ln_g  = (const float*)d_in[16];
  const float* ln_b  = (const float*)d_in[17];
  const float* ff_w1 = (const float*)d_in[18];
  const float* ff_dw = (const float*)d_in[19];
  const float* ff_w2 = (const float*)d_in[20];

  const size_t NC = 8388608;  // B*N*C
  char* w = (char*)d_ws;
  float* X  = (float*)w; w += NC * 4;   // residual stream, fp32
  bhalf* Xb = (bhalf*)w; w += NC * 2;   // bf16 mirror of X (GEMM input)
  bhalf* M  = (bhalf*)w; w += NC * 2;   // mask NHWC (constant across blocks)
  bhalf* Qb = (bhalf*)w; w += NC * 2;
  bhalf* Kb = (bhalf*)w; w += NC * 2;
  bhalf* Vb = (bhalf*)w; w += NC * 2;
  bhalf* VG = (bhalf*)w; w += NC * 2;
  bhalf* T1 = (bhalf*)w; w += NC * 2;
  bhalf* T2 = (bhalf*)w; w += NC * 2;
  bhalf* T3 = (bhalf*)w; w += NC * 2;
  bhalf* Pb = (bhalf*)w; w += NC * 2;
  float* Sb    = (float*)w; w += 2048 * 4;  // S, nq, nk contiguous for one memset
  float* nqb   = (float*)w; w += 128 * 4;
  float* nkb   = (float*)w; w += 128 * 4;
  float* attnT = (float*)w; w += 2048 * 4;

  nchw2nhwc<0><<<2048, 256, 0, stream>>>(x_in, X, Xb);
  nchw2nhwc<1><<<2048, 256, 0, stream>>>(mask_in, M, nullptr);

  for (int i = 0; i < 3; ++i) {
    // mask-guided branch: m1 = M@w1+b1 ; am = sigmoid(dw5(m1@w2+b2)+db) ; MA = m1*(am+1)
    gemm64<EP_BIAS, 0><<<GEMM_GRID, 256, 0, stream>>>(M, mm_w1 + i*4096, mm_b1 + i*64, T1, nullptr, nullptr, nullptr, 64, 0);
    gemm64<EP_BIAS, 0><<<GEMM_GRID, 256, 0, stream>>>(T1, mm_w2 + i*4096, mm_b2 + i*64, T2, nullptr, nullptr, nullptr, 64, 0);
    dwconv<5, 2><<<DW_GRID, 256, 0, stream>>>(T2, mm_dw + i*1600, mm_db + i*64, T1, T3, 64, 0);
    // Q, K, V from bf16 Xb (V also emits VG = V * MA)
    gemm64<EP_NONE, 0><<<GEMM_GRID, 256, 0, stream>>>(Xb, Wq + i*4096, nullptr, Qb, nullptr, nullptr, nullptr, 64, 0);
    gemm64<EP_NONE, 0><<<GEMM_GRID, 256, 0, stream>>>(Xb, Wk + i*4096, nullptr, Kb, nullptr, nullptr, nullptr, 64, 0);
    gemm64<EP_GATE, 0><<<GEMM_GRID, 256, 0, stream>>>(Xb, Wv + i*4096, nullptr, Vb, T3, VG, nullptr, 64, 0);
    // channel attention
    hipMemsetAsync(Sb, 0, (2048 + 128 + 128) * 4, stream);
    attn_partial<<<dim3(32, 4, 2), 256, 0, stream>>>(Qb, Kb, Sb, nqb, nkb);
    attn_softmax<<<8, 64, 0, stream>>>(Sb, nqb, nkb, resc + i*4, attnT);
    // positional branch on ungated V
    dwconv<3, 1><<<DW_GRID, 256, 0, stream>>>(Vb, pe1 + i*576, nullptr, nullptr, T1, 64, 0);
    dwconv<3, 0><<<DW_GRID, 256, 0, stream>>>(T1, pe2 + i*576, nullptr, nullptr, Pb, 64, 0);
    // o = attn-apply(VG); X += o@Wp + bp + P   (MSA residual); refresh Xb
    attnapply_kernel<<<GEMM_GRID, 256, 0, stream>>>(VG, attnT, T2);
    gemm64<EP_RESID, 0><<<GEMM_GRID, 256, 0, stream>>>(T2, Wp + i*4096, bp + i*64, X, Pb, nullptr, Xb, 64, 0);
    // FFN: X += W2( gelu(dw3( gelu(LN(X)@W1) )) ), 4 chunks of 64 hidden channels
    ln_kernel<<<GEMM_GRID, 256, 0, stream>>>(X, ln_g + i*64, ln_b + i*64, T1);
    for (int ch = 0; ch < 4; ++ch) {
      gemm64<EP_GELU, 0><<<GEMM_GRID, 256, 0, stream>>>(T1, ff_w1 + i*16384, nullptr, T2, nullptr, nullptr, nullptr, 256, ch*64);
      dwconv<3, 1><<<DW_GRID, 256, 0, stream>>>(T2, ff_dw + i*2304, nullptr, nullptr, T3, 256, ch*64);
      gemm64<EP_ACC, 0><<<GEMM_GRID, 256, 0, stream>>>(T3, ff_w2 + i*16384 + ch*4096, nullptr, X, nullptr, nullptr,
                                                       (ch == 3) ? Xb : nullptr, 64, 0);
    }
  }
  nhwc2nchw<<<2048, 256, 0, stream>>>(X, (float*)d_out);
}

// Round 5
// 1266.388 us; speedup vs baseline: 3.0925x; 3.0925x over previous
//
#include <hip/hip_runtime.h>
#include <math.h>

// HGSA: 3x (mask-guided channel-attention MSA + LN + convFFN) on [2,64,256,256].
// External I/O fp32. Internal activations bf16, residual stream X fp32 (+bf16
// mirror Xb), weights bf16 in LDS.
// R2: dwconv 8ch/thread. R3/R4: row-per-thread VALU gemm with acc[64] spills
// no matter the launch bounds (VGPR 52-64, scratch leaks 100-200MB/dispatch).
// R5: MFMA gemm — wave computes 16x64 tile, 4x f32x4 accumulators (16 VGPR),
// W^T bf16 staged in LDS, LDS-transpose epilogue for coalesced stores.
// ln_kernel restructured to 4 threads/row (kills its v[64] spill risk).

typedef unsigned short bhalf;
typedef unsigned int u32;
typedef __attribute__((ext_vector_type(8))) short bf16x8;
typedef __attribute__((ext_vector_type(4))) float f32x4;

#define DW_GRID 4096        // (B*N*64/8)/256
#define GEMM_GRID 2048      // 131072 rows / 64 rows per block
#define LN_GRID 2048

__device__ __forceinline__ float bf2f(bhalf b) {
  union { u32 u; float f; } c; c.u = ((u32)b) << 16; return c.f;
}
__device__ __forceinline__ bhalf f2bf(float f) {
  union { float f; u32 u; } c; c.f = f;
  u32 lsb = (c.u >> 16) & 1u;
  c.u += 0x7fffu + lsb;           // round-to-nearest-even
  return (bhalf)(c.u >> 16);
}
__device__ __forceinline__ u32 pack2bf(float a, float b) {
  return (u32)f2bf(a) | ((u32)f2bf(b) << 16);
}
__device__ __forceinline__ void unpack2(u32 p, float& a, float& b) {
  union { u32 u; float f; } c0, c1;
  c0.u = p << 16; c1.u = p & 0xffff0000u;
  a = c0.f; b = c1.f;
}
__device__ __forceinline__ void unpack8(uint4 u, float* f) {
  unpack2(u.x, f[0], f[1]); unpack2(u.y, f[2], f[3]);
  unpack2(u.z, f[4], f[5]); unpack2(u.w, f[6], f[7]);
}
__device__ __forceinline__ float gelu_f(float v) {   // exact gelu
  return 0.5f * v * (1.0f + erff(v * 0.70710678118654752440f));
}
__device__ __forceinline__ uint4 pack16(const float* v) {
  uint4 s;
  s.x = pack2bf(v[0], v[1]); s.y = pack2bf(v[2], v[3]);
  s.z = pack2bf(v[4], v[5]); s.w = pack2bf(v[6], v[7]);
  return s;
}

// ---------------- transposes ----------------
// MODE 0: x -> fp32 X AND bf16 Xb.  MODE 1: mask -> bf16 only.
template<int MODE>
__global__ __launch_bounds__(256) void nchw2nhwc(const float* __restrict__ in,
                                                 void* __restrict__ out,
                                                 bhalf* __restrict__ out2) {
  __shared__ float tile[64][65];
  int t = threadIdx.x;
  int b = blockIdx.x >> 10;
  int n0 = (blockIdx.x & 1023) << 6;
  #pragma unroll
  for (int j = 0; j < 16; ++j) {
    int idx = j * 256 + t;
    int c = idx >> 6, nn = idx & 63;
    tile[c][nn] = in[(((size_t)(b * 64 + c)) << 16) + n0 + nn];
  }
  __syncthreads();
  #pragma unroll
  for (int j = 0; j < 16; ++j) {
    int idx = j * 256 + t;
    int nn = idx >> 6, c = idx & 63;
    size_t o = ((((size_t)b << 16) + n0 + nn) << 6) + c;
    float v = tile[c][nn];
    if (MODE == 0) { ((float*)out)[o] = v; out2[o] = f2bf(v); }
    else           { ((bhalf*)out)[o] = f2bf(v); }
  }
}

__global__ __launch_bounds__(256) void nhwc2nchw(const float* __restrict__ in,
                                                 float* __restrict__ out) {
  __shared__ float tile[64][65];
  int t = threadIdx.x;
  int b = blockIdx.x >> 10;
  int n0 = (blockIdx.x & 1023) << 6;
  #pragma unroll
  for (int j = 0; j < 16; ++j) {
    int idx = j * 256 + t;
    int nn = idx >> 6, c = idx & 63;
    tile[c][nn] = in[((((size_t)b << 16) + n0 + nn) << 6) + c];
  }
  __syncthreads();
  #pragma unroll
  for (int j = 0; j < 16; ++j) {
    int idx = j * 256 + t;
    int c = idx >> 6, nn = idx & 63;
    out[(((size_t)(b * 64 + c)) << 16) + n0 + nn] = tile[c][nn];
  }
}

// ---------------- MFMA GEMM: [131072 x 64] @ [64 x 64] ----------------
#define EP_NONE 0
#define EP_BIAS 1
#define EP_GELU 2
#define EP_ACC  3   // fp32 out_ += result; optional bf16 mirror write (xbout)
#define EP_GATE 4   // store V (bf16); also store VG = V * aux
#define EP_RESID 5  // fp32 out_(X) += result + bias + aux(P bf16); writes xbout

// Block = 4 waves; wave w computes rows [blk*64 + w*16, +16) x all 64 cols.
// K=64 split into 2 chunks of 32 for mfma_f32_16x16x32_bf16.
// A-frag (A[m=lane&15][k=quad*8+j]) loads straight from global (16B/lane).
// B-frag from LDS W^T bf16 [n][k] stride 72 (16B-aligned ds_read_b128).
// C/D: col=lane&15, row=quad*4+reg -> transpose via LDS (stride 68, 2-way max)
// then per-thread row-segment epilogue with coalesced vector stores.
template<int EP>
__global__ __launch_bounds__(256) void gemm64m(
    const bhalf* __restrict__ in_, const float* __restrict__ w,
    const float* __restrict__ bias, void* __restrict__ out_,
    const bhalf* __restrict__ aux, bhalf* __restrict__ outg,
    bhalf* __restrict__ xbout, int wstride, int coloff)
{
  __shared__ bhalf WT[64 * 72];     // W^T, [n][k]
  __shared__ float Cs[64 * 68];     // epilogue transpose buffer
  __shared__ float bias_s[64];
  int t = threadIdx.x;
  #pragma unroll
  for (int i = 0; i < 16; ++i) {
    int idx = i * 256 + t;
    int k = idx >> 6, n = idx & 63;
    WT[n * 72 + k] = f2bf(w[(size_t)k * wstride + coloff + n]);
  }
  if ((EP == EP_BIAS || EP == EP_RESID) && t < 64) bias_s[t] = bias[t];
  __syncthreads();

  int wv = t >> 6;
  int lane = t & 63;
  int lm = lane & 15;
  int q = lane >> 4;
  size_t row0 = ((size_t)blockIdx.x << 6) + (wv << 4);

  const bhalf* arow = in_ + ((row0 + lm) << 6) + (q << 3);
  bf16x8 a0 = *(const bf16x8*)(arow);
  bf16x8 a1 = *(const bf16x8*)(arow + 32);

  f32x4 acc[4];
  #pragma unroll
  for (int nt = 0; nt < 4; ++nt) {
    const bhalf* bp_ = &WT[(nt * 16 + lm) * 72 + (q << 3)];
    bf16x8 b0 = *(const bf16x8*)(bp_);
    bf16x8 b1 = *(const bf16x8*)(bp_ + 32);
    f32x4 c = {0.f, 0.f, 0.f, 0.f};
    c = __builtin_amdgcn_mfma_f32_16x16x32_bf16(a0, b0, c, 0, 0, 0);
    c = __builtin_amdgcn_mfma_f32_16x16x32_bf16(a1, b1, c, 0, 0, 0);
    acc[nt] = c;
  }
  #pragma unroll
  for (int nt = 0; nt < 4; ++nt) {
    #pragma unroll
    for (int r = 0; r < 4; ++r)
      Cs[((wv << 4) + (q << 2) + r) * 68 + (nt << 4) + lm] = acc[nt][r];
  }
  __syncthreads();

  // epilogue: thread -> row rr = t>>2, cols [c0, c0+16)
  int rr = t >> 2, c0 = (t & 3) << 4;
  size_t grow = ((size_t)blockIdx.x << 6) + rr;
  float v[16];
  #pragma unroll
  for (int j = 0; j < 4; ++j) {
    float4 u = *(const float4*)&Cs[rr * 68 + c0 + 4 * j];
    v[4*j] = u.x; v[4*j+1] = u.y; v[4*j+2] = u.z; v[4*j+3] = u.w;
  }

  if (EP == EP_ACC) {
    float* xr = (float*)out_ + (grow << 6) + c0;
    #pragma unroll
    for (int j = 0; j < 4; ++j) {
      float4* x4 = (float4*)(xr + 4 * j);
      float4 u = *x4;
      u.x += v[4*j]; u.y += v[4*j+1]; u.z += v[4*j+2]; u.w += v[4*j+3];
      *x4 = u;
      v[4*j] = u.x; v[4*j+1] = u.y; v[4*j+2] = u.z; v[4*j+3] = u.w;
    }
    if (xbout) {
      bhalf* xb = xbout + (grow << 6) + c0;
      ((uint4*)xb)[0] = pack16(v);
      ((uint4*)xb)[1] = pack16(v + 8);
    }
  } else if (EP == EP_RESID) {
    float* xr = (float*)out_ + (grow << 6) + c0;
    const bhalf* pr = aux + (grow << 6) + c0;
    uint4 p0 = ((const uint4*)pr)[0], p1 = ((const uint4*)pr)[1];
    float pf[16];
    unpack8(p0, pf); unpack8(p1, pf + 8);
    #pragma unroll
    for (int j = 0; j < 4; ++j) {
      float4* x4 = (float4*)(xr + 4 * j);
      float4 u = *x4;
      u.x += v[4*j]   + bias_s[c0 + 4*j]     + pf[4*j];
      u.y += v[4*j+1] + bias_s[c0 + 4*j + 1] + pf[4*j+1];
      u.z += v[4*j+2] + bias_s[c0 + 4*j + 2] + pf[4*j+2];
      u.w += v[4*j+3] + bias_s[c0 + 4*j + 3] + pf[4*j+3];
      *x4 = u;
      v[4*j] = u.x; v[4*j+1] = u.y; v[4*j+2] = u.z; v[4*j+3] = u.w;
    }
    bhalf* xb = xbout + (grow << 6) + c0;
    ((uint4*)xb)[0] = pack16(v);
    ((uint4*)xb)[1] = pack16(v + 8);
  } else {
    #pragma unroll
    for (int j = 0; j < 16; ++j) {
      if (EP == EP_BIAS) v[j] += bias_s[c0 + j];
      if (EP == EP_GELU) v[j] = gelu_f(v[j]);
    }
    bhalf* ob = (bhalf*)out_ + (grow << 6) + c0;
    ((uint4*)ob)[0] = pack16(v);
    ((uint4*)ob)[1] = pack16(v + 8);
    if (EP == EP_GATE) {
      const bhalf* mr = aux + (grow << 6) + c0;
      uint4 m0 = ((const uint4*)mr)[0], m1q = ((const uint4*)mr)[1];
      float mf[16];
      unpack8(m0, mf); unpack8(m1q, mf + 8);
      float gvv[16];
      #pragma unroll
      for (int j = 0; j < 16; ++j) gvv[j] = v[j] * mf[j];
      bhalf* gb = outg + (grow << 6) + c0;
      ((uint4*)gb)[0] = pack16(gvv);
      ((uint4*)gb)[1] = pack16(gvv + 8);
    }
  }
}

// ---------------- depthwise conv KxK SAME, NHWC, 64-channel slab ----------------
// 8 channels per thread via uint4 bf16 loads (16 B/lane).
// EPI: 0 = plain, 1 = gelu, 2 = mask gate: out = m1 * (sigmoid(acc + db) + 1)
template<int KS, int EPI>
__global__ __launch_bounds__(256) void dwconv(
    const bhalf* __restrict__ in, const float* __restrict__ wt,
    const float* __restrict__ db, const bhalf* __restrict__ m1,
    bhalf* __restrict__ out, int wstride, int woff)
{
  __shared__ float Ws[KS * KS * 64];
  __shared__ float db_s[64];
  int t = threadIdx.x;
  for (int idx = t; idx < KS * KS * 64; idx += 256) {
    int tap = idx >> 6, c = idx & 63;
    Ws[idx] = wt[tap * wstride + woff + c];
  }
  if (EPI == 2 && t < 64) db_s[t] = db[t];
  __syncthreads();
  size_t gid8 = (size_t)blockIdx.x * 256 + t;   // unit = 8 channels
  int c0 = (int)(gid8 & 7) << 3;
  size_t p = gid8 >> 3;
  int wx = (int)(p & 255), hy = (int)((p >> 8) & 255);
  size_t bb = p >> 16;
  const int R = KS >> 1;
  float acc[8];
  #pragma unroll
  for (int j = 0; j < 8; ++j) acc[j] = 0.0f;
  #pragma unroll
  for (int kh = 0; kh < KS; ++kh) {
    int y = hy + kh - R;
    if ((unsigned)y >= 256u) continue;
    #pragma unroll
    for (int kw = 0; kw < KS; ++kw) {
      int xw = wx + kw - R;
      if ((unsigned)xw >= 256u) continue;
      size_t off = (((bb << 8) + (size_t)y) << 8) + (size_t)xw;
      uint4 u = *(const uint4*)(in + (off << 6) + c0);
      float f[8];
      unpack8(u, f);
      const float* wr = &Ws[(kh * KS + kw) * 64 + c0];
      #pragma unroll
      for (int j = 0; j < 8; ++j) acc[j] += f[j] * wr[j];
    }
  }
  float r[8];
  if (EPI == 0) {
    #pragma unroll
    for (int j = 0; j < 8; ++j) r[j] = acc[j];
  } else if (EPI == 1) {
    #pragma unroll
    for (int j = 0; j < 8; ++j) r[j] = gelu_f(acc[j]);
  } else {
    uint4 mu = *(const uint4*)(m1 + (p << 6) + c0);
    float mf[8];
    unpack8(mu, mf);
    #pragma unroll
    for (int j = 0; j < 8; ++j) {
      float am = 1.0f / (1.0f + expf(-(acc[j] + db_s[c0 + j])));
      r[j] = mf[j] * (am + 1.0f);
    }
  }
  uint4 s;
  s.x = pack2bf(r[0], r[1]); s.y = pack2bf(r[2], r[3]);
  s.z = pack2bf(r[4], r[5]); s.w = pack2bf(r[6], r[7]);
  *(uint4*)(out + (p << 6) + c0) = s;
}

// ---------------- channel attention: S = K^T Q (per head) + channel norms ----------------
// grid: (chunk=32, h=4, b=2); 256 thr = (d 0..15, e4 0..3, row-quarter 0..3)
__global__ __launch_bounds__(256) void attn_partial(
    const bhalf* __restrict__ Q, const bhalf* __restrict__ K,
    float* __restrict__ S, float* __restrict__ nq, float* __restrict__ nk)
{
  __shared__ float Qs[1024], Ks[1024];
  int t = threadIdx.x;
  int d = t & 15, e4 = (t >> 4) & 3;
  int r0 = (t >> 6) << 4;
  int h = blockIdx.y, b = blockIdx.z;
  size_t base = ((((size_t)b << 16) + ((size_t)blockIdx.x << 11)) << 6) + (h << 4);
  int lr = t >> 2, lc = (t & 3) << 2;
  float4 acc = {0,0,0,0};
  float4 qss = {0,0,0,0};
  float kss = 0.0f;
  for (int s = 0; s < 32; ++s) {
    size_t g = base + ((size_t)(s * 64 + lr) << 6) + lc;
    uint2 qu = *(const uint2*)(Q + g);
    uint2 ku = *(const uint2*)(K + g);
    __syncthreads();
    float4 qf, kf;
    unpack2(qu.x, qf.x, qf.y); unpack2(qu.y, qf.z, qf.w);
    unpack2(ku.x, kf.x, kf.y); unpack2(ku.y, kf.z, kf.w);
    *(float4*)&Qs[t << 2] = qf;
    *(float4*)&Ks[t << 2] = kf;
    __syncthreads();
    #pragma unroll
    for (int rr = 0; rr < 16; ++rr) {
      int r = r0 + rr;
      float kv = Ks[(r << 4) + d];
      float4 qv = *(const float4*)&Qs[(r << 4) + (e4 << 2)];
      acc.x += kv * qv.x; acc.y += kv * qv.y; acc.z += kv * qv.z; acc.w += kv * qv.w;
      qss.x += qv.x * qv.x; qss.y += qv.y * qv.y; qss.z += qv.z * qv.z; qss.w += qv.w * qv.w;
      kss += kv * kv;
    }
  }
  float* Sp = S + ((((size_t)b * 4 + h) * 16 + d) << 4) + (e4 << 2);
  atomicAdd(Sp + 0, acc.x); atomicAdd(Sp + 1, acc.y);
  atomicAdd(Sp + 2, acc.z); atomicAdd(Sp + 3, acc.w);
  if (d == 0) {
    float* qp = nq + b * 64 + (h << 4) + (e4 << 2);
    atomicAdd(qp + 0, qss.x); atomicAdd(qp + 1, qss.y);
    atomicAdd(qp + 2, qss.z); atomicAdd(qp + 3, qss.w);
  }
  if (e4 == 0) atomicAdd(nk + b * 64 + (h << 4) + d, kss);
}

// softmax over e of S[d,e]*rescale/(max(||k_d||,eps)*max(||q_e||,eps)); writes TRANSPOSED [b][h][e][d]
__global__ void attn_softmax(const float* __restrict__ S, const float* __restrict__ nq,
                             const float* __restrict__ nk, const float* __restrict__ resc,
                             float* __restrict__ attnT)
{
  int b = blockIdx.x >> 2, h = blockIdx.x & 3;
  int d = threadIdx.x;
  if (d >= 16) return;
  float r = resc[h];
  float nkd = fmaxf(sqrtf(nk[b * 64 + h * 16 + d]), 1e-6f);
  float a[16];
  float m = -1e30f;
  #pragma unroll
  for (int e = 0; e < 16; ++e) {
    float nqe = fmaxf(sqrtf(nq[b * 64 + h * 16 + e]), 1e-6f);
    float v = S[(((b * 4 + h) * 16 + d) << 4) + e] * r / (nkd * nqe);
    a[e] = v;
    m = fmaxf(m, v);
  }
  float sum = 0.f;
  #pragma unroll
  for (int e = 0; e < 16; ++e) { a[e] = expf(a[e] - m); sum += a[e]; }
  float inv = 1.0f / sum;
  #pragma unroll
  for (int e = 0; e < 16; ++e)
    attnT[(((b * 4 + h) * 16 + e) << 4) + d] = a[e] * inv;
}

// o[n, h*16+d] = sum_e attnT[h][e][d] * VG[n, h*16+e]  (block-diagonal per-head 16x16)
__global__ __launch_bounds__(256) void attnapply_kernel(
    const bhalf* __restrict__ vg, const float* __restrict__ attnT, bhalf* __restrict__ outO)
{
  __shared__ float As[1024];
  int t = threadIdx.x;
  int b = blockIdx.x >> 8;
  #pragma unroll
  for (int j = 0; j < 4; ++j) As[j * 256 + t] = attnT[b * 1024 + j * 256 + t];
  __syncthreads();
  size_t row = (size_t)blockIdx.x * 256 + t;
  const uint4* gv = (const uint4*)(vg + (row << 6));
  bhalf* orow = outO + (row << 6);
  #pragma unroll
  for (int h = 0; h < 4; ++h) {
    uint4 u0 = gv[2 * h], u1 = gv[2 * h + 1];
    float ve[16];
    unpack8(u0, ve); unpack8(u1, ve + 8);
    float4 oh0 = {0,0,0,0}, oh1 = {0,0,0,0}, oh2 = {0,0,0,0}, oh3 = {0,0,0,0};
    #pragma unroll
    for (int e = 0; e < 16; ++e) {
      const float4* ar = (const float4*)&As[(h * 16 + e) << 4];
      float vv = ve[e];
      float4 a0 = ar[0], a1 = ar[1], a2 = ar[2], a3 = ar[3];
      oh0.x += vv*a0.x; oh0.y += vv*a0.y; oh0.z += vv*a0.z; oh0.w += vv*a0.w;
      oh1.x += vv*a1.x; oh1.y += vv*a1.y; oh1.z += vv*a1.z; oh1.w += vv*a1.w;
      oh2.x += vv*a2.x; oh2.y += vv*a2.y; oh2.z += vv*a2.z; oh2.w += vv*a2.w;
      oh3.x += vv*a3.x; oh3.y += vv*a3.y; oh3.z += vv*a3.z; oh3.w += vv*a3.w;
    }
    uint4 s0, s1;
    s0.x = pack2bf(oh0.x, oh0.y); s0.y = pack2bf(oh0.z, oh0.w);
    s0.z = pack2bf(oh1.x, oh1.y); s0.w = pack2bf(oh1.z, oh1.w);
    s1.x = pack2bf(oh2.x, oh2.y); s1.y = pack2bf(oh2.z, oh2.w);
    s1.z = pack2bf(oh3.x, oh3.y); s1.w = pack2bf(oh3.z, oh3.w);
    ((uint4*)(orow + h * 16))[0] = s0;
    ((uint4*)(orow + h * 16))[1] = s1;
  }
}

// ---------------- LayerNorm over C=64, 4 threads/row (no big reg arrays) ----------------
__global__ __launch_bounds__(256) void ln_kernel(
    const float* __restrict__ x, const float* __restrict__ g,
    const float* __restrict__ bb, bhalf* __restrict__ out)
{
  __shared__ float gs[64], bs[64];
  __shared__ float red1[256], red2[256];
  int t = threadIdx.x;
  if (t < 64) { gs[t] = g[t]; bs[t] = bb[t]; }
  int rr = t >> 2, seg = t & 3;
  size_t row = ((size_t)blockIdx.x << 6) + rr;
  const float4* xv = (const float4*)(x + (row << 6) + (seg << 4));
  float v[16];
  #pragma unroll
  for (int j = 0; j < 4; ++j) {
    float4 u = xv[j];
    v[4*j] = u.x; v[4*j+1] = u.y; v[4*j+2] = u.z; v[4*j+3] = u.w;
  }
  float s1 = 0.f, s2 = 0.f;
  #pragma unroll
  for (int j = 0; j < 16; ++j) { s1 += v[j]; s2 += v[j] * v[j]; }
  red1[t] = s1; red2[t] = s2;
  __syncthreads();
  float fs1 = red1[rr*4] + red1[rr*4+1] + red1[rr*4+2] + red1[rr*4+3];
  float fs2 = red2[rr*4] + red2[rr*4+1] + red2[rr*4+2] + red2[rr*4+3];
  float mu = fs1 * 0.015625f;
  float var = fs2 * 0.015625f - mu * mu;
  float rstd = rsqrtf(var + 1e-5f);
  int c0 = seg << 4;
  float r[16];
  #pragma unroll
  for (int j = 0; j < 16; ++j)
    r[j] = (v[j] - mu) * rstd * gs[c0 + j] + bs[c0 + j];
  bhalf* ob = out + (row << 6) + c0;
  ((uint4*)ob)[0] = pack16(r);
  ((uint4*)ob)[1] = pack16(r + 8);
}

// ---------------- host orchestration ----------------
extern "C" void kernel_launch(void* const* d_in, const int* in_sizes, int n_in,
                              void* d_out, int out_size, void* d_ws, size_t ws_size,
                              hipStream_t stream)
{
  (void)in_sizes; (void)n_in; (void)out_size; (void)ws_size;
  const float* x_in    = (const float*)d_in[0];
  const float* mask_in = (const float*)d_in[1];
  const float* Wq    = (const float*)d_in[2];
  const float* Wk    = (const float*)d_in[3];
  const float* Wv    = (const float*)d_in[4];
  const float* resc  = (const float*)d_in[5];
  const float* Wp    = (const float*)d_in[6];
  const float* bp    = (const float*)d_in[7];
  const float* pe1   = (const float*)d_in[8];
  const float* pe2   = (const float*)d_in[9];
  const float* mm_w1 = (const float*)d_in[10];
  const float* mm_b1 = (const float*)d_in[11];
  const float* mm_w2 = (const float*)d_in[12];
  const float* mm_b2 = (const float*)d_in[13];
  const float* mm_dw = (const float*)d_in[14];
  const float* mm_db = (const float*)d_in[15];
  const float* ln_g  = (const float*)d_in[16];
  const float* ln_b  = (const float*)d_in[17];
  const float* ff_w1 = (const float*)d_in[18];
  const float* ff_dw = (const float*)d_in[19];
  const float* ff_w2 = (const float*)d_in[20];

  const size_t NC = 8388608;  // B*N*C
  char* w = (char*)d_ws;
  float* X  = (float*)w; w += NC * 4;   // residual stream, fp32
  bhalf* Xb = (bhalf*)w; w += NC * 2;   // bf16 mirror of X (GEMM input)
  bhalf* M  = (bhalf*)w; w += NC * 2;   // mask NHWC (constant across blocks)
  bhalf* Qb = (bhalf*)w; w += NC * 2;
  bhalf* Kb = (bhalf*)w; w += NC * 2;
  bhalf* Vb = (bhalf*)w; w += NC * 2;
  bhalf* VG = (bhalf*)w; w += NC * 2;
  bhalf* T1 = (bhalf*)w; w += NC * 2;
  bhalf* T2 = (bhalf*)w; w += NC * 2;
  bhalf* T3 = (bhalf*)w; w += NC * 2;
  bhalf* Pb = (bhalf*)w; w += NC * 2;
  float* Sb    = (float*)w; w += 2048 * 4;  // S, nq, nk contiguous for one memset
  float* nqb   = (float*)w; w += 128 * 4;
  float* nkb   = (float*)w; w += 128 * 4;
  float* attnT = (float*)w; w += 2048 * 4;

  nchw2nhwc<0><<<2048, 256, 0, stream>>>(x_in, X, Xb);
  nchw2nhwc<1><<<2048, 256, 0, stream>>>(mask_in, M, nullptr);

  for (int i = 0; i < 3; ++i) {
    // mask-guided branch: m1 = M@w1+b1 ; am = sigmoid(dw5(m1@w2+b2)+db) ; MA = m1*(am+1)
    gemm64m<EP_BIAS><<<GEMM_GRID, 256, 0, stream>>>(M, mm_w1 + i*4096, mm_b1 + i*64, T1, nullptr, nullptr, nullptr, 64, 0);
    gemm64m<EP_BIAS><<<GEMM_GRID, 256, 0, stream>>>(T1, mm_w2 + i*4096, mm_b2 + i*64, T2, nullptr, nullptr, nullptr, 64, 0);
    dwconv<5, 2><<<DW_GRID, 256, 0, stream>>>(T2, mm_dw + i*1600, mm_db + i*64, T1, T3, 64, 0);
    // Q, K, V from bf16 Xb (V also emits VG = V * MA)
    gemm64m<EP_NONE><<<GEMM_GRID, 256, 0, stream>>>(Xb, Wq + i*4096, nullptr, Qb, nullptr, nullptr, nullptr, 64, 0);
    gemm64m<EP_NONE><<<GEMM_GRID, 256, 0, stream>>>(Xb, Wk + i*4096, nullptr, Kb, nullptr, nullptr, nullptr, 64, 0);
    gemm64m<EP_GATE><<<GEMM_GRID, 256, 0, stream>>>(Xb, Wv + i*4096, nullptr, Vb, T3, VG, nullptr, 64, 0);
    // channel attention
    hipMemsetAsync(Sb, 0, (2048 + 128 + 128) * 4, stream);
    attn_partial<<<dim3(32, 4, 2), 256, 0, stream>>>(Qb, Kb, Sb, nqb, nkb);
    attn_softmax<<<8, 64, 0, stream>>>(Sb, nqb, nkb, resc + i*4, attnT);
    // positional branch on ungated V
    dwconv<3, 1><<<DW_GRID, 256, 0, stream>>>(Vb, pe1 + i*576, nullptr, nullptr, T1, 64, 0);
    dwconv<3, 0><<<DW_GRID, 256, 0, stream>>>(T1, pe2 + i*576, nullptr, nullptr, Pb, 64, 0);
    // o = attn-apply(VG); X += o@Wp + bp + P   (MSA residual); refresh Xb
    attnapply_kernel<<<512, 256, 0, stream>>>(VG, attnT, T2);
    gemm64m<EP_RESID><<<GEMM_GRID, 256, 0, stream>>>(T2, Wp + i*4096, bp + i*64, X, Pb, nullptr, Xb, 64, 0);
    // FFN: X += W2( gelu(dw3( gelu(LN(X)@W1) )) ), 4 chunks of 64 hidden channels
    ln_kernel<<<LN_GRID, 256, 0, stream>>>(X, ln_g + i*64, ln_b + i*64, T1);
    for (int ch = 0; ch < 4; ++ch) {
      gemm64m<EP_GELU><<<GEMM_GRID, 256, 0, stream>>>(T1, ff_w1 + i*16384, nullptr, T2, nullptr, nullptr, nullptr, 256, ch*64);
      dwconv<3, 1><<<DW_GRID, 256, 0, stream>>>(T2, ff_dw + i*2304, nullptr, nullptr, T3, 256, ch*64);
      gemm64m<EP_ACC><<<GEMM_GRID, 256, 0, stream>>>(T3, ff_w2 + i*16384 + ch*4096, nullptr, X, nullptr, nullptr,
                                                     (ch == 3) ? Xb : nullptr, 64, 0);
    }
  }
  nhwc2nchw<<<2048, 256, 0, stream>>>(X, (float*)d_out);
}